// Round 2
// baseline (2591.580 us; speedup 1.0000x reference)
//
#include <hip/hip_runtime.h>
#include <hip/hip_cooperative_groups.h>

namespace cg = cooperative_groups;

typedef unsigned short u16;
typedef unsigned int u32;
typedef __attribute__((ext_vector_type(8))) short bf16x8;
typedef __attribute__((ext_vector_type(4))) float f32x4;

// B=64 T=20 D_IN=512 H=512 D_ENC=2048 P=196 D_ATT=512
#define NB 64
#define NT 20
#define NH 512
#define NP 196
#define NE 2048
#define NA 512

__device__ __forceinline__ u16 f2bf(float f) {
  u32 b = __float_as_uint(f);
  return (u16)((b + 0x7FFFu + ((b >> 16) & 1u)) >> 16);
}
__device__ __forceinline__ float bf2f(u16 u) { return __uint_as_float(((u32)u) << 16); }
__device__ __forceinline__ float tanh_fast(float x) {
  float xc = fminf(fmaxf(x, -15.f), 15.f);
  float e2 = __builtin_amdgcn_exp2f(xc * 2.885390082f);
  return (e2 - 1.f) * __builtin_amdgcn_rcpf(e2 + 1.f);
}
__device__ __forceinline__ float sigmoid_fast(float x) {
  return __builtin_amdgcn_rcpf(1.f + __builtin_amdgcn_exp2f(x * -1.44269504f));
}

// ---------------- f32 -> bf16 convert (vectorized, grid-stride) ----------------
__global__ __launch_bounds__(256) void conv_bf16(const float4* __restrict__ src,
                                                 u16* __restrict__ dst, int n4) {
  int i = blockIdx.x * 256 + threadIdx.x;
  int stride = gridDim.x * 256;
  for (; i < n4; i += stride) {
    float4 v = src[i];
    u32 lo = (u32)f2bf(v.x) | ((u32)f2bf(v.y) << 16);
    u32 hi = (u32)f2bf(v.z) | ((u32)f2bf(v.w) << 16);
    *(uint2*)(dst + (size_t)i * 4) = make_uint2(lo, hi);
  }
}

// ------------- transpose f32 [K][512] (+row offset) -> bf16 [z*512+n][K] -------------
__global__ __launch_bounds__(256) void transpose_w(const float* __restrict__ W0,
                                                   const float* __restrict__ W1,
                                                   const float* __restrict__ W2,
                                                   const float* __restrict__ W3,
                                                   u16* __restrict__ dst, int row_off, int K) {
  const float* src = blockIdx.z == 0 ? W0 : blockIdx.z == 1 ? W1 : blockIdx.z == 2 ? W2 : W3;
  __shared__ float tile[32][33];
  int k0 = blockIdx.x * 32, n0 = blockIdx.y * 32;
  int tx = threadIdx.x & 31, ty = threadIdx.x >> 5;  // 32 x 8
#pragma unroll
  for (int i = 0; i < 4; ++i)
    tile[ty + i * 8][tx] = src[(size_t)(row_off + k0 + ty + i * 8) * 512 + n0 + tx];
  __syncthreads();
#pragma unroll
  for (int i = 0; i < 4; ++i) {
    int n = n0 + ty + i * 8, k = k0 + tx;
    dst[((size_t)blockIdx.z * 512 + n) * K + k] = f2bf(tile[tx][ty + i * 8]);
  }
}

// ---------------- generic bf16 MFMA GEMM: C[M][N] = A[M][K] * BT[N][K]^T (+bias) ----------------
// BM=BN=128, BK=64, 4 waves (2x2), wave tile 64x64 = 4x4 MFMA frags. XOR-swizzled LDS.
template <bool OUT_BF16, bool BIAS>
__global__ __launch_bounds__(256) void gemm_bf16(const u16* __restrict__ A,
                                                 const u16* __restrict__ BT,
                                                 const float* __restrict__ bias,
                                                 void* __restrict__ Cout, int M, int N, int K) {
  __shared__ u16 lA[128 * 64];
  __shared__ u16 lB[128 * 64];
  const int tid = threadIdx.x;
  const int lane = tid & 63;
  const int wid = tid >> 6;
  const int m0 = blockIdx.x * 128, n0 = blockIdx.y * 128;
  const int wm = (wid >> 1) * 64, wn = (wid & 1) * 64;
  f32x4 acc[4][4] = {};

  for (int k0 = 0; k0 < K; k0 += 64) {
    __syncthreads();
#pragma unroll
    for (int it = 0; it < 4; ++it) {
      int c = tid + it * 256;           // chunk in [0,1024): 16B chunks of 128x64 bf16 tile
      int r = c >> 3, c7 = c & 7;
      uint4 va = *(const uint4*)(A + (size_t)(m0 + r) * K + k0 + c7 * 8);
      uint4 vb = *(const uint4*)(BT + (size_t)(n0 + r) * K + k0 + c7 * 8);
      int ldsoff = r * 64 + ((c7 ^ (r & 7)) * 8);  // u16 units, swizzled
      *(uint4*)(lA + ldsoff) = va;
      *(uint4*)(lB + ldsoff) = vb;
    }
    __syncthreads();
#pragma unroll
    for (int kk = 0; kk < 2; ++kk) {
      int kchunk = kk * 4 + (lane >> 4);
      bf16x8 af[4], bg[4];
#pragma unroll
      for (int i = 0; i < 4; ++i) {
        int row = wm + i * 16 + (lane & 15);
        af[i] = *(const bf16x8*)(lA + row * 64 + ((kchunk ^ (row & 7)) * 8));
        int rowb = wn + i * 16 + (lane & 15);
        bg[i] = *(const bf16x8*)(lB + rowb * 64 + ((kchunk ^ (rowb & 7)) * 8));
      }
#pragma unroll
      for (int i = 0; i < 4; ++i)
#pragma unroll
        for (int j = 0; j < 4; ++j)
          acc[i][j] = __builtin_amdgcn_mfma_f32_16x16x32_bf16(af[i], bg[j], acc[i][j], 0, 0, 0);
    }
  }
#pragma unroll
  for (int i = 0; i < 4; ++i) {
    int m = m0 + wm + i * 16 + ((lane >> 4) * 4);
#pragma unroll
    for (int j = 0; j < 4; ++j) {
      int n = n0 + wn + j * 16 + (lane & 15);
      float bv = BIAS ? bias[n] : 0.f;
#pragma unroll
      for (int r = 0; r < 4; ++r) {
        float val = acc[i][j][r] + bv;
        if (OUT_BF16)
          ((u16*)Cout)[(size_t)(m + r) * N + n] = f2bf(val);
        else
          ((float*)Cout)[(size_t)(m + r) * N + n] = val;
      }
    }
  }
}

// ================= fused recurrence: one cooperative kernel, 20 steps =================
// grid 256 x 512 threads (1 block/CU, 8 waves/CU). 3 grid.sync per step.
// Phase A: e[b,p]      (block = b*4 + pchunk)
// Phase B: softmax+ctx (block = b*4 + cchunk)
// Phase C: gates+cell+hWa partials (blocks 0..127 = nt*4+mt)
struct StepParams {
  const u16* fpb;
  const u16* cnnb;
  const u16* whct;
  const float* xw;
  const float* bi;
  const float* bf;
  const float* bc;
  const float* bo;
  const float* wah;
  const float* v;
  float* ebuf;
  u16* ctxb;
  float* cbuf;
  float* hwap;
  u16* hbuf;
  float* out;
};

__global__ __launch_bounds__(512) void step_all(StepParams P) {
  cg::grid_group grid = cg::this_grid();
  const int blk = blockIdx.x;
  const int tid = threadIdx.x;
  const int lane = tid & 63;
  const int wid = tid >> 6;
  __shared__ float sm[2048];  // 8KB, phase-aliased

  for (int t = 0; t < NT; ++t) {
    // ---------------- Phase A: e[b,p] = sum_a tanh(fp + hWa) * v ----------------
    {
      const int b = blk >> 2, pc = blk & 3;
      float s = 0.f;
      if (t > 0) {
#pragma unroll 8
        for (int nt = 0; nt < 32; ++nt) s += P.hwap[((size_t)nt * 64 + b) * 512 + tid];
      }
      sm[tid] = s;            // hwa[a]
      sm[512 + tid] = P.v[tid];  // vv[a]
      __syncthreads();
      float hw[8], vr[8];
#pragma unroll
      for (int j = 0; j < 8; ++j) {
        hw[j] = sm[lane * 8 + j];
        vr[j] = sm[512 + lane * 8 + j];
      }
      for (int pi = wid; pi < 49; pi += 8) {
        int p = pc * 49 + pi;
        const u16* fp = P.fpb + ((size_t)b * NP + p) * 512 + lane * 8;
        uint4 raw = *(const uint4*)fp;
        u32 w[4] = {raw.x, raw.y, raw.z, raw.w};
        float part = 0.f;
#pragma unroll
        for (int j = 0; j < 8; ++j) {
          u16 u = (u16)(w[j >> 1] >> ((j & 1) * 16));
          part += tanh_fast(bf2f(u) + hw[j]) * vr[j];
        }
#pragma unroll
        for (int off = 32; off > 0; off >>= 1) part += __shfl_xor(part, off);
        if (lane == 0) P.ebuf[b * NP + p] = part;
      }
    }
    grid.sync();

    // ---------------- Phase B: softmax(e[b,:]) then ctx ----------------
    {
      const int b = blk >> 2, cc = blk & 3;
      float ev = (tid < NP) ? P.ebuf[b * NP + tid] : -3e38f;
      sm[tid] = ev;
      __syncthreads();
      for (int s = 256; s > 0; s >>= 1) {
        if (tid < s) sm[tid] = fmaxf(sm[tid], sm[tid + s]);
        __syncthreads();
      }
      float mx = sm[0];
      __syncthreads();
      float w = (tid < NP) ? __builtin_amdgcn_exp2f((ev - mx) * 1.44269504f) : 0.f;
      sm[tid] = w;
      __syncthreads();
      for (int s = 256; s > 0; s >>= 1) {
        if (tid < s) sm[tid] += sm[tid + s];
        __syncthreads();
      }
      float inv = __builtin_amdgcn_rcpf(sm[0]);
      if (tid < NP) sm[1024 + tid] = w * inv;  // alp[p]
      __syncthreads();

      const int half = tid >> 8, l2 = tid & 255;
      const int c = cc * 512 + l2 * 2;
      const u16* base = P.cnnb + (size_t)b * NP * NE + c;
      float a0 = 0.f, a1 = 0.f;
#pragma unroll 4
      for (int p = half; p < NP; p += 2) {
        float al = sm[1024 + p];
        u32 two = *(const u32*)(base + (size_t)p * NE);
        a0 += al * bf2f((u16)(two & 0xFFFFu));
        a1 += al * bf2f((u16)(two >> 16));
      }
      sm[tid] = a0;
      sm[512 + tid] = a1;
      __syncthreads();
      if (tid < 256) {
        float s0 = sm[tid] + sm[tid + 256];
        float s1 = sm[512 + tid] + sm[512 + tid + 256];
        u32 packed = (u32)f2bf(s0) | ((u32)f2bf(s1) << 16);
        *(u32*)(P.ctxb + (size_t)b * NE + c) = packed;
      }
    }
    grid.sync();

    // ---------------- Phase C: gates GEMM + cell + hWa partials (blocks 0..127) ----------------
    if (blk < 128) {
      const int mt = blk & 3, nt = blk >> 2;
      const int g = wid & 3, kh = wid >> 2;
      const int brow = mt * 16 + (lane & 15);
      const int ncol = nt * 16 + (lane & 15);
      const u16* Bp = P.whct + (size_t)(g * 512 + ncol) * 2560;
      const u16* hprev = P.hbuf + (size_t)(t & 1) * NB * 512;
      const u16* hA = hprev + (size_t)brow * 512;
      const u16* cA = P.ctxb + (size_t)brow * 2048 - 512;  // indexed by k in [512,2560)
      const int klo = kh * 1280 + ((lane >> 4) * 8);
      f32x4 acc = {0.f, 0.f, 0.f, 0.f};
      if (kh == 0) {
        if (t > 0) {  // h == 0 at t == 0
#pragma unroll 4
          for (int ks = 0; ks < 16; ++ks) {
            int k = klo + ks * 32;
            bf16x8 a = *(const bf16x8*)(hA + k);
            bf16x8 bb = *(const bf16x8*)(Bp + k);
            acc = __builtin_amdgcn_mfma_f32_16x16x32_bf16(a, bb, acc, 0, 0, 0);
          }
        }
#pragma unroll 4
        for (int ks = 16; ks < 40; ++ks) {
          int k = klo + ks * 32;
          bf16x8 a = *(const bf16x8*)(cA + k);
          bf16x8 bb = *(const bf16x8*)(Bp + k);
          acc = __builtin_amdgcn_mfma_f32_16x16x32_bf16(a, bb, acc, 0, 0, 0);
        }
      } else {
#pragma unroll 4
        for (int ks = 0; ks < 40; ++ks) {
          int k = klo + ks * 32;
          bf16x8 a = *(const bf16x8*)(cA + k);
          bf16x8 bb = *(const bf16x8*)(Bp + k);
          acc = __builtin_amdgcn_mfma_f32_16x16x32_bf16(a, bb, acc, 0, 0, 0);
        }
      }

      // pre[g][m][n] = sm[g*256+m*16+n]; hlds[m][n] = sm[1024+m*16+n]
      const int rrow = (lane >> 4) * 4;
      if (kh == 0) {
#pragma unroll
        for (int r = 0; r < 4; ++r) sm[g * 256 + (rrow + r) * 16 + (lane & 15)] = acc[r];
      }
      __syncthreads();
      if (kh == 1) {
#pragma unroll
        for (int r = 0; r < 4; ++r) sm[g * 256 + (rrow + r) * 16 + (lane & 15)] += acc[r];
      }
      __syncthreads();

      if (tid < 256) {
        const int m = tid >> 4, n = tid & 15;
        const int b = mt * 16 + m, ng = nt * 16 + n;
        size_t xwo = ((size_t)b * NT + t) * 2048 + ng;
        float ip = sm[0 * 256 + m * 16 + n] + P.xw[xwo] + P.bi[ng];
        float fp = sm[1 * 256 + m * 16 + n] + P.xw[xwo + 512] + P.bf[ng];
        float cp = sm[2 * 256 + m * 16 + n] + P.xw[xwo + 1024] + P.bc[ng];
        float op = sm[3 * 256 + m * 16 + n] + P.xw[xwo + 1536] + P.bo[ng];
        float it = sigmoid_fast(ip), ft = sigmoid_fast(fp), ot = sigmoid_fast(op);
        float ctl = tanh_fast(cp);
        float cold = (t > 0) ? P.cbuf[(size_t)b * 512 + ng] : 0.f;
        float cn = ft * cold + it * ctl;
        float hn = ot * tanh_fast(cn);
        P.cbuf[(size_t)b * 512 + ng] = cn;
        u16* hnext = P.hbuf + (size_t)((t + 1) & 1) * NB * 512;
        hnext[(size_t)b * 512 + ng] = f2bf(hn);
        P.out[((size_t)b * NT + t) * 512 + ng] = hn;
        if (t == NT - 1) {
          P.out[(size_t)NB * NT * 512 + (size_t)b * 512 + ng] = hn;
          P.out[(size_t)NB * NT * 512 + (size_t)NB * 512 + (size_t)b * 512 + ng] = cn;
        }
        sm[1024 + m * 16 + n] = hn;
      }
      __syncthreads();

      // hWa partial: hwap[nt][b][a] = sum_{j<16} h[b][nt*16+j] * Wa_h[nt*16+j][a]
      {
        const int a = tid;  // 512 threads = 512 a
        float wa[16];
#pragma unroll
        for (int j = 0; j < 16; ++j) wa[j] = P.wah[(size_t)(nt * 16 + j) * 512 + a];
#pragma unroll
        for (int bl = 0; bl < 16; ++bl) {
          float s = 0.f;
#pragma unroll
          for (int j = 0; j < 16; ++j) s += sm[1024 + bl * 16 + j] * wa[j];
          P.hwap[((size_t)nt * 64 + mt * 16 + bl) * 512 + a] = s;
        }
      }
    }
    grid.sync();
  }
}

// ======================= host launcher =======================
extern "C" void kernel_launch(void* const* d_in, const int* in_sizes, int n_in, void* d_out,
                              int out_size, void* d_ws, size_t ws_size, hipStream_t stream) {
  const float* x = (const float*)d_in[0];
  const float* cnn = (const float*)d_in[1];
  const float* Wi = (const float*)d_in[2];
  const float* bi = (const float*)d_in[3];
  const float* Wf = (const float*)d_in[4];
  const float* bfv = (const float*)d_in[5];
  const float* Wc = (const float*)d_in[6];
  const float* bc = (const float*)d_in[7];
  const float* Wo = (const float*)d_in[8];
  const float* bo = (const float*)d_in[9];
  const float* Waf = (const float*)d_in[10];
  const float* Wah = (const float*)d_in[11];
  const float* ba = (const float*)d_in[12];
  const float* v = (const float*)d_in[13];
  float* out = (float*)d_out;

  char* base = (char*)d_ws;
  size_t off = 0;
  auto alloc = [&](size_t bytes) {
    char* r = base + off;
    off += (bytes + 255) & ~(size_t)255;
    return r;
  };
  u16* cnnb = (u16*)alloc((size_t)NB * NP * NE * 2);       // 51.4 MB
  u16* fpb = (u16*)alloc((size_t)NB * NP * NA * 2);        // 12.8 MB
  u16* whct = (u16*)alloc((size_t)4 * 512 * 2560 * 2);     // 10.5 MB
  u16* wxt = (u16*)alloc((size_t)4 * 512 * 512 * 2);       // 2 MB
  u16* waft = (u16*)alloc((size_t)512 * 2048 * 2);         // 2 MB
  u16* xb = (u16*)alloc((size_t)NB * NT * 512 * 2);        // 1.3 MB
  float* xw = (float*)alloc((size_t)NB * NT * 2048 * 4);   // 10.5 MB
  u16* hbuf = (u16*)alloc((size_t)2 * NB * 512 * 2);       // 128 KB (double buffer)
  float* cbuf = (float*)alloc((size_t)NB * 512 * 4);       // 128 KB
  u16* ctxb = (u16*)alloc((size_t)NB * 2048 * 2);          // 256 KB
  float* ebuf = (float*)alloc((size_t)NB * NP * 4);        // 50 KB
  float* hwap = (float*)alloc((size_t)32 * NB * 512 * 4);  // 4 MB

  (void)ws_size;
  (void)in_sizes;
  (void)n_in;
  (void)out_size;

  // conversions
  conv_bf16<<<2048, 256, 0, stream>>>((const float4*)cnn, cnnb, (NB * NP * NE) / 4);
  conv_bf16<<<640, 256, 0, stream>>>((const float4*)x, xb, (NB * NT * 512) / 4);

  // weight transposes (f32 [K][512] -> bf16 [g*512+n][K])
  {
    dim3 g1(2560 / 32, 16, 4);
    transpose_w<<<g1, 256, 0, stream>>>(Wi, Wf, Wc, Wo, whct, 512, 2560);
    dim3 g2(512 / 32, 16, 4);
    transpose_w<<<g2, 256, 0, stream>>>(Wi, Wf, Wc, Wo, wxt, 0, 512);
    dim3 g3(2048 / 32, 16, 1);
    transpose_w<<<g3, 256, 0, stream>>>(Waf, Waf, Waf, Waf, waft, 0, 2048);
  }

  // feat_proj = cnn @ Wa_feat + ba  -> bf16 [12544][512]
  {
    dim3 g(12544 / 128, 512 / 128);
    gemm_bf16<true, true><<<g, 256, 0, stream>>>(cnnb, waft, ba, fpb, 12544, 512, 2048);
  }
  // xw = x @ W[:512,:] (4 gates)  -> f32 [1280][2048]  (biases added in step_all)
  {
    dim3 g(1280 / 128, 2048 / 128);
    gemm_bf16<false, false><<<g, 256, 0, stream>>>(xb, wxt, nullptr, xw, 1280, 2048, 512);
  }

  // fused 20-step recurrence (cooperative: grid-wide sync between phases)
  {
    StepParams sp;
    sp.fpb = fpb;
    sp.cnnb = cnnb;
    sp.whct = whct;
    sp.xw = xw;
    sp.bi = bi;
    sp.bf = bfv;
    sp.bc = bc;
    sp.bo = bo;
    sp.wah = Wah;
    sp.v = v;
    sp.ebuf = ebuf;
    sp.ctxb = ctxb;
    sp.cbuf = cbuf;
    sp.hwap = hwap;
    sp.hbuf = hbuf;
    sp.out = out;
    void* args[] = {&sp};
    hipLaunchCooperativeKernel((void*)step_all, dim3(256), dim3(512), args, 0, stream);
  }
}

// Round 3
// 986.771 us; speedup vs baseline: 2.6263x; 2.6263x over previous
//
#include <hip/hip_runtime.h>

typedef unsigned short u16;
typedef unsigned int u32;
typedef __attribute__((ext_vector_type(8))) short bf16x8;
typedef __attribute__((ext_vector_type(4))) float f32x4;

// B=64 T=20 D_IN=512 H=512 D_ENC=2048 P=196 D_ATT=512
#define NB 64
#define NT 20
#define NH 512
#define NP 196
#define NE 2048
#define NA 512

__device__ __forceinline__ u16 f2bf(float f) {
  u32 b = __float_as_uint(f);
  return (u16)((b + 0x7FFFu + ((b >> 16) & 1u)) >> 16);
}
__device__ __forceinline__ float bf2f(u16 u) { return __uint_as_float(((u32)u) << 16); }
__device__ __forceinline__ float tanh_fast(float x) {
  float xc = fminf(fmaxf(x, -15.f), 15.f);
  float e2 = __builtin_amdgcn_exp2f(xc * 2.885390082f);
  return (e2 - 1.f) * __builtin_amdgcn_rcpf(e2 + 1.f);
}
__device__ __forceinline__ float sigmoid_fast(float x) {
  return __builtin_amdgcn_rcpf(1.f + __builtin_amdgcn_exp2f(x * -1.44269504f));
}

// ---------------- f32 -> bf16 convert (vectorized, grid-stride) ----------------
__global__ __launch_bounds__(256) void conv_bf16(const float4* __restrict__ src,
                                                 u16* __restrict__ dst, int n4) {
  int i = blockIdx.x * 256 + threadIdx.x;
  int stride = gridDim.x * 256;
  for (; i < n4; i += stride) {
    float4 v = src[i];
    u32 lo = (u32)f2bf(v.x) | ((u32)f2bf(v.y) << 16);
    u32 hi = (u32)f2bf(v.z) | ((u32)f2bf(v.w) << 16);
    *(uint2*)(dst + (size_t)i * 4) = make_uint2(lo, hi);
  }
}

// ---------------- x [b][t][512] f32 -> xbT [t][b][512] bf16 ----------------
__global__ __launch_bounds__(128) void conv_x(const float* __restrict__ x,
                                              u16* __restrict__ xbT) {
  int b = blockIdx.x, t = blockIdx.y, tid = threadIdx.x;
  float4 v = *(const float4*)(x + ((size_t)b * NT + t) * 512 + tid * 4);
  u32 lo = (u32)f2bf(v.x) | ((u32)f2bf(v.y) << 16);
  u32 hi = (u32)f2bf(v.z) | ((u32)f2bf(v.w) << 16);
  *(uint2*)(xbT + ((size_t)t * NB + b) * 512 + tid * 4) = make_uint2(lo, hi);
}

// ------------- transpose f32 [K][512] (+row offset) -> bf16 [z*512+n][K] -------------
__global__ __launch_bounds__(256) void transpose_w(const float* __restrict__ W0,
                                                   const float* __restrict__ W1,
                                                   const float* __restrict__ W2,
                                                   const float* __restrict__ W3,
                                                   u16* __restrict__ dst, int row_off, int K) {
  const float* src = blockIdx.z == 0 ? W0 : blockIdx.z == 1 ? W1 : blockIdx.z == 2 ? W2 : W3;
  __shared__ float tile[32][33];
  int k0 = blockIdx.x * 32, n0 = blockIdx.y * 32;
  int tx = threadIdx.x & 31, ty = threadIdx.x >> 5;  // 32 x 8
#pragma unroll
  for (int i = 0; i < 4; ++i)
    tile[ty + i * 8][tx] = src[(size_t)(row_off + k0 + ty + i * 8) * 512 + n0 + tx];
  __syncthreads();
#pragma unroll
  for (int i = 0; i < 4; ++i) {
    int n = n0 + ty + i * 8, k = k0 + tx;
    dst[((size_t)blockIdx.z * 512 + n) * K + k] = f2bf(tile[tx][ty + i * 8]);
  }
}

// ---------------- generic bf16 MFMA GEMM: C[M][N] = A[M][K] * BT[N][K]^T (+bias) ----------------
template <bool OUT_BF16, bool BIAS>
__global__ __launch_bounds__(256) void gemm_bf16(const u16* __restrict__ A,
                                                 const u16* __restrict__ BT,
                                                 const float* __restrict__ bias,
                                                 void* __restrict__ Cout, int M, int N, int K) {
  __shared__ u16 lA[128 * 64];
  __shared__ u16 lB[128 * 64];
  const int tid = threadIdx.x;
  const int lane = tid & 63;
  const int wid = tid >> 6;
  const int m0 = blockIdx.x * 128, n0 = blockIdx.y * 128;
  const int wm = (wid >> 1) * 64, wn = (wid & 1) * 64;
  f32x4 acc[4][4] = {};

  for (int k0 = 0; k0 < K; k0 += 64) {
    __syncthreads();
#pragma unroll
    for (int it = 0; it < 4; ++it) {
      int c = tid + it * 256;
      int r = c >> 3, c7 = c & 7;
      uint4 va = *(const uint4*)(A + (size_t)(m0 + r) * K + k0 + c7 * 8);
      uint4 vb = *(const uint4*)(BT + (size_t)(n0 + r) * K + k0 + c7 * 8);
      int ldsoff = r * 64 + ((c7 ^ (r & 7)) * 8);
      *(uint4*)(lA + ldsoff) = va;
      *(uint4*)(lB + ldsoff) = vb;
    }
    __syncthreads();
#pragma unroll
    for (int kk = 0; kk < 2; ++kk) {
      int kchunk = kk * 4 + (lane >> 4);
      bf16x8 af[4], bg[4];
#pragma unroll
      for (int i = 0; i < 4; ++i) {
        int row = wm + i * 16 + (lane & 15);
        af[i] = *(const bf16x8*)(lA + row * 64 + ((kchunk ^ (row & 7)) * 8));
        int rowb = wn + i * 16 + (lane & 15);
        bg[i] = *(const bf16x8*)(lB + rowb * 64 + ((kchunk ^ (rowb & 7)) * 8));
      }
#pragma unroll
      for (int i = 0; i < 4; ++i)
#pragma unroll
        for (int j = 0; j < 4; ++j)
          acc[i][j] = __builtin_amdgcn_mfma_f32_16x16x32_bf16(af[i], bg[j], acc[i][j], 0, 0, 0);
    }
  }
#pragma unroll
  for (int i = 0; i < 4; ++i) {
    int m = m0 + wm + i * 16 + ((lane >> 4) * 4);
#pragma unroll
    for (int j = 0; j < 4; ++j) {
      int n = n0 + wn + j * 16 + (lane & 15);
      float bv = BIAS ? bias[n] : 0.f;
#pragma unroll
      for (int r = 0; r < 4; ++r) {
        float val = acc[i][j][r] + bv;
        if (OUT_BF16)
          ((u16*)Cout)[(size_t)(m + r) * N + n] = f2bf(val);
        else
          ((float*)Cout)[(size_t)(m + r) * N + n] = val;
      }
    }
  }
}

// ============ fused attention: e + softmax + ctx, one block per (b, col-half) ============
// grid 128 = b*2 + ch, 1024 threads (16 waves).
__global__ __launch_bounds__(1024) void attn_ctx(const u16* __restrict__ fpb,
                                                 const float* __restrict__ hwap,
                                                 const float* __restrict__ v,
                                                 const u16* __restrict__ cnnb,
                                                 u16* __restrict__ ctxb, int t) {
  const int b = blockIdx.x >> 1;
  const int ch = blockIdx.x & 1;  // which 1024 cols of ctx
  const int tid = threadIdx.x;
  const int lane = tid & 63, wid = tid >> 6;
  __shared__ float hwa[512];
  __shared__ float vv[512];
  __shared__ float sm[256];
  __shared__ float alp[200];
  __shared__ float red[8192];  // ctx partials [pg8][cu128][8]; red[0..255] doubles as e[]

  // hwa[a] = sum_nt hwap[nt][b][a]   (h==0 at t==0)
  if (tid < 512) {
    float s = 0.f;
    if (t > 0) {
#pragma unroll 8
      for (int nt = 0; nt < 32; ++nt) s += hwap[((size_t)nt * 64 + b) * 512 + tid];
    }
    hwa[tid] = s;
    vv[tid] = v[tid];
  }
  if (tid >= 196 && tid < 256) red[tid] = -3e38f;  // pad e[]
  __syncthreads();

  // e[p] = sum_a tanh(fp + hwa) * v   (one p per wave per iter)
  float hw[8], vr[8];
#pragma unroll
  for (int j = 0; j < 8; ++j) {
    hw[j] = hwa[lane * 8 + j];
    vr[j] = vv[lane * 8 + j];
  }
  for (int p = wid; p < NP; p += 16) {
    const u16* fp = fpb + ((size_t)b * NP + p) * 512 + lane * 8;
    uint4 raw = *(const uint4*)fp;
    u32 w[4] = {raw.x, raw.y, raw.z, raw.w};
    float part = 0.f;
#pragma unroll
    for (int j = 0; j < 8; ++j) {
      u16 u = (u16)(w[j >> 1] >> ((j & 1) * 16));
      part += tanh_fast(bf2f(u) + hw[j]) * vr[j];
    }
#pragma unroll
    for (int off = 32; off > 0; off >>= 1) part += __shfl_xor(part, off);
    if (lane == 0) red[p] = part;
  }
  __syncthreads();

  // softmax over 196 (threads <256 active in reductions; all hit barriers)
  float ev = (tid < 256) ? red[tid] : -3e38f;
  if (tid < 256) sm[tid] = ev;
  __syncthreads();
  for (int s = 128; s > 0; s >>= 1) {
    if (tid < s) sm[tid] = fmaxf(sm[tid], sm[tid + s]);
    __syncthreads();
  }
  float mx = sm[0];
  __syncthreads();
  float w = (tid < NP) ? __builtin_amdgcn_exp2f((ev - mx) * 1.44269504f) : 0.f;
  if (tid < 256) sm[tid] = w;
  __syncthreads();
  for (int s = 128; s > 0; s >>= 1) {
    if (tid < s) sm[tid] += sm[tid + s];
    __syncthreads();
  }
  float inv = __builtin_amdgcn_rcpf(sm[0]);
  if (tid < NP) alp[tid] = w * inv;
  __syncthreads();

  // ctx: 8 p-groups x 128 col-units of 8 (uint4 loads), LDS-reduce over p-groups
  {
    const int pg = tid >> 7, cu = tid & 127;
    const int col = ch * 1024 + cu * 8;
    const u16* base = cnnb + (size_t)b * NP * NE + col;
    float acc[8] = {};
    for (int i = 0; i < 25; ++i) {
      int p = pg + i * 8;
      if (p < NP) {
        float al = alp[p];
        uint4 raw = *(const uint4*)(base + (size_t)p * NE);
        u32 wds[4] = {raw.x, raw.y, raw.z, raw.w};
#pragma unroll
        for (int j = 0; j < 8; ++j)
          acc[j] += al * bf2f((u16)(wds[j >> 1] >> ((j & 1) * 16)));
      }
    }
#pragma unroll
    for (int j = 0; j < 8; ++j) red[tid * 8 + j] = acc[j];
    __syncthreads();
    if (tid < 512) {
      const int cu2 = tid >> 2, jp = tid & 3;
      float s0 = 0.f, s1 = 0.f;
#pragma unroll
      for (int g = 0; g < 8; ++g) {
        s0 += red[g * 1024 + cu2 * 8 + jp * 2];
        s1 += red[g * 1024 + cu2 * 8 + jp * 2 + 1];
      }
      u32 packed = (u32)f2bf(s0) | ((u32)f2bf(s1) << 16);
      *(u32*)(ctxb + (size_t)b * NE + ch * 1024 + cu2 * 8 + jp * 2) = packed;
    }
  }
}

// ---------------- gates GEMM (M=64,N=2048,K=2560) + LSTM cell + hWa partials ----------------
// grid 128 = (nt<<2 | mt), 512 thr = 8 waves = (kh in {0,1}) x (gate g in {0..3}).
__global__ __launch_bounds__(512) void gates_kernel(
    const u16* __restrict__ hprev, const u16* __restrict__ ctxb, const u16* __restrict__ whct,
    const float* __restrict__ xw, const float* __restrict__ bi, const float* __restrict__ bfg,
    const float* __restrict__ bc, const float* __restrict__ bo, float* __restrict__ cbuf,
    float* __restrict__ out, const float* __restrict__ wah, float* __restrict__ hwap,
    u16* __restrict__ hnext, int t) {
  int mt = blockIdx.x & 3, nt = blockIdx.x >> 2;
  int tid = threadIdx.x, lane = tid & 63, wid = tid >> 6;
  int g = wid & 3, kh = wid >> 2;
  int brow = mt * 16 + (lane & 15);
  int ncol = nt * 16 + (lane & 15);
  const u16* Bp = whct + (size_t)(g * 512 + ncol) * 2560;
  const u16* hA = hprev + (size_t)brow * 512;
  const u16* cA = ctxb + (size_t)brow * 2048 - 512;  // indexed by k in [512,2560)
  int klo = kh * 1280 + ((lane >> 4) * 8);
  f32x4 acc = {0.f, 0.f, 0.f, 0.f};
  if (kh == 0) {
    if (t > 0) {  // h == 0 at t == 0
#pragma unroll 4
      for (int ks = 0; ks < 16; ++ks) {
        int k = klo + ks * 32;
        bf16x8 a = *(const bf16x8*)(hA + k);
        bf16x8 bb = *(const bf16x8*)(Bp + k);
        acc = __builtin_amdgcn_mfma_f32_16x16x32_bf16(a, bb, acc, 0, 0, 0);
      }
    }
#pragma unroll 4
    for (int ks = 16; ks < 40; ++ks) {
      int k = klo + ks * 32;
      bf16x8 a = *(const bf16x8*)(cA + k);
      bf16x8 bb = *(const bf16x8*)(Bp + k);
      acc = __builtin_amdgcn_mfma_f32_16x16x32_bf16(a, bb, acc, 0, 0, 0);
    }
  } else {
#pragma unroll 4
    for (int ks = 0; ks < 40; ++ks) {
      int k = klo + ks * 32;
      bf16x8 a = *(const bf16x8*)(cA + k);
      bf16x8 bb = *(const bf16x8*)(Bp + k);
      acc = __builtin_amdgcn_mfma_f32_16x16x32_bf16(a, bb, acc, 0, 0, 0);
    }
  }

  __shared__ float pre[4][16][16];
  __shared__ float hlds[16][16];
  int rrow = (lane >> 4) * 4;
  if (kh == 0) {
#pragma unroll
    for (int r = 0; r < 4; ++r) pre[g][rrow + r][lane & 15] = acc[r];
  }
  __syncthreads();
  if (kh == 1) {
#pragma unroll
    for (int r = 0; r < 4; ++r) pre[g][rrow + r][lane & 15] += acc[r];
  }
  __syncthreads();

  if (tid < 256) {
    int m = tid >> 4, n = tid & 15;
    int b = mt * 16 + m, ng = nt * 16 + n;
    size_t xwo = ((size_t)t * NB + b) * 2048 + ng;  // xw layout [t][b][2048]
    float ip = pre[0][m][n] + xw[xwo] + bi[ng];
    float fp = pre[1][m][n] + xw[xwo + 512] + bfg[ng];
    float cp = pre[2][m][n] + xw[xwo + 1024] + bc[ng];
    float op = pre[3][m][n] + xw[xwo + 1536] + bo[ng];
    float it = sigmoid_fast(ip), ft = sigmoid_fast(fp), ot = sigmoid_fast(op);
    float ctl = tanh_fast(cp);
    float cold = (t > 0) ? cbuf[(size_t)b * 512 + ng] : 0.f;
    float cn = ft * cold + it * ctl;
    float hn = ot * tanh_fast(cn);
    cbuf[(size_t)b * 512 + ng] = cn;
    hnext[(size_t)b * 512 + ng] = f2bf(hn);
    out[((size_t)b * NT + t) * 512 + ng] = hn;
    if (t == NT - 1) {
      out[(size_t)NB * NT * 512 + (size_t)b * 512 + ng] = hn;
      out[(size_t)NB * NT * 512 + (size_t)NB * 512 + (size_t)b * 512 + ng] = cn;
    }
    hlds[m][n] = hn;
  }
  __syncthreads();

  // hWa partial: hwap[nt][b][a] = sum_{j<16} h[b][nt*16+j] * Wa_h[nt*16+j][a]
  {
    int a = tid;
    float wa[16];
#pragma unroll
    for (int j = 0; j < 16; ++j) wa[j] = wah[(size_t)(nt * 16 + j) * 512 + a];
#pragma unroll
    for (int bl = 0; bl < 16; ++bl) {
      float s = 0.f;
#pragma unroll
      for (int j = 0; j < 16; ++j) s += hlds[bl][j] * wa[j];
      hwap[((size_t)nt * 64 + mt * 16 + bl) * 512 + a] = s;
    }
  }
}

// ======================= host launcher =======================
extern "C" void kernel_launch(void* const* d_in, const int* in_sizes, int n_in, void* d_out,
                              int out_size, void* d_ws, size_t ws_size, hipStream_t stream) {
  const float* x = (const float*)d_in[0];
  const float* cnn = (const float*)d_in[1];
  const float* Wi = (const float*)d_in[2];
  const float* bi = (const float*)d_in[3];
  const float* Wf = (const float*)d_in[4];
  const float* bfv = (const float*)d_in[5];
  const float* Wc = (const float*)d_in[6];
  const float* bc = (const float*)d_in[7];
  const float* Wo = (const float*)d_in[8];
  const float* bo = (const float*)d_in[9];
  const float* Waf = (const float*)d_in[10];
  const float* Wah = (const float*)d_in[11];
  const float* ba = (const float*)d_in[12];
  const float* v = (const float*)d_in[13];
  float* out = (float*)d_out;

  char* base = (char*)d_ws;
  size_t off = 0;
  auto alloc = [&](size_t bytes) {
    char* r = base + off;
    off += (bytes + 255) & ~(size_t)255;
    return r;
  };
  u16* cnnb = (u16*)alloc((size_t)NB * NP * NE * 2);       // 51.4 MB
  u16* fpb = (u16*)alloc((size_t)NB * NP * NA * 2);        // 12.8 MB
  u16* whct = (u16*)alloc((size_t)4 * 512 * 2560 * 2);     // 10.5 MB
  u16* wxt = (u16*)alloc((size_t)4 * 512 * 512 * 2);       // 2 MB
  u16* waft = (u16*)alloc((size_t)512 * 2048 * 2);         // 2 MB
  u16* xbT = (u16*)alloc((size_t)NT * NB * 512 * 2);       // 1.3 MB  [t][b][512]
  float* xw = (float*)alloc((size_t)NT * NB * 2048 * 4);   // 10.5 MB [t][b][2048]
  u16* hbuf = (u16*)alloc((size_t)2 * NB * 512 * 2);       // 128 KB (double buffer)
  float* cbuf = (float*)alloc((size_t)NB * 512 * 4);       // 128 KB
  u16* ctxb = (u16*)alloc((size_t)NB * 2048 * 2);          // 256 KB
  float* hwap = (float*)alloc((size_t)32 * NB * 512 * 4);  // 4 MB

  (void)ws_size;
  (void)in_sizes;
  (void)n_in;
  (void)out_size;

  // conversions / transposes
  conv_bf16<<<2048, 256, 0, stream>>>((const float4*)cnn, cnnb, (NB * NP * NE) / 4);
  conv_x<<<dim3(NB, NT), 128, 0, stream>>>(x, xbT);
  {
    dim3 g1(2560 / 32, 16, 4);
    transpose_w<<<g1, 256, 0, stream>>>(Wi, Wf, Wc, Wo, whct, 512, 2560);
    dim3 g2(512 / 32, 16, 4);
    transpose_w<<<g2, 256, 0, stream>>>(Wi, Wf, Wc, Wo, wxt, 0, 512);
    dim3 g3(2048 / 32, 16, 1);
    transpose_w<<<g3, 256, 0, stream>>>(Waf, Waf, Waf, Waf, waft, 0, 2048);
  }

  // feat_proj = cnn @ Wa_feat + ba  -> bf16 [12544][512]
  {
    dim3 g(12544 / 128, 512 / 128);
    gemm_bf16<true, true><<<g, 256, 0, stream>>>(cnnb, waft, ba, fpb, 12544, 512, 2048);
  }
  // xw = xT @ W[:512,:] (4 gates) -> f32 [t*64+b][2048]
  {
    dim3 g(1280 / 128, 2048 / 128);
    gemm_bf16<false, false><<<g, 256, 0, stream>>>(xbT, wxt, nullptr, xw, 1280, 2048, 512);
  }

  // 20-step recurrence: 2 kernels per step
  for (int t = 0; t < NT; ++t) {
    const u16* hprev = hbuf + (size_t)(t & 1) * NB * 512;
    u16* hnext = hbuf + (size_t)((t + 1) & 1) * NB * 512;
    attn_ctx<<<128, 1024, 0, stream>>>(fpb, hwap, v, cnnb, ctxb, t);
    gates_kernel<<<128, 512, 0, stream>>>(hprev, ctxb, whct, xw, bi, bfv, bc, bo, cbuf, out, Wah,
                                          hwap, hnext, t);
  }
}